// Round 5
// baseline (562.964 us; speedup 1.0000x reference)
//
#include <hip/hip_runtime.h>

#define N_EDGES 1000000
#define HID 128
#define ME 64          // edges per block (16 per wave, end-to-end)

typedef unsigned short ushort;
typedef unsigned int uint;
typedef __attribute__((ext_vector_type(8))) short short8;
typedef __attribute__((ext_vector_type(4))) float f32x4;

__device__ __forceinline__ float blo(uint u) { return __builtin_bit_cast(float, u << 16); }
__device__ __forceinline__ float bhi(uint u) { return __builtin_bit_cast(float, u & 0xffff0000u); }
__device__ __forceinline__ ushort f2bfbits(float f) {
  uint u = __builtin_bit_cast(uint, f);
  return (ushort)((u + 0x7fffu + ((u >> 16) & 1u)) >> 16);  // RNE
}
__device__ __forceinline__ uint cvtpk(float a, float b) {
  uint r;
  asm("v_cvt_pk_bf16_f32 %0, %1, %2" : "=v"(r) : "v"(a), "v"(b));
  return r;  // lo = bf16(a), hi = bf16(b)
}
__device__ __forceinline__ uint cvtpk_abs(float a, float b) {
  uint r;
  asm("v_cvt_pk_bf16_f32 %0, abs(%1), abs(%2)" : "=v"(r) : "v"(a), "v"(b));
  return r;  // lo = bf16(|a|), hi = bf16(|b|)
}
// XOR-swizzled element index into a [64][128] ushort LDS tile.
__device__ __forceinline__ int sidx(int r, int c) {
  return r * 128 + (c ^ ((r & 7) << 3));
}

// Pack W (row-major [K][128] f32) into B-fragment order for mfma_f32_16x16x32_bf16.
// W1p kb 0..15: k = kb*32 + (lane>>4)*8 + j (zs,zd,prod,absdiff).
// W1p kb 16..17 (tail chunk, 64 cols): c = (kb-16)*32+(lane>>4)*8+j;
//   c==0 -> k512 (dist); c in [2,34) -> k 511+c (lr_emb); else zero row.
__global__ void prep_kernel(const float* __restrict__ W1, const float* __restrict__ W2,
                            ushort* __restrict__ W1p, ushort* __restrict__ W2p) {
  const int t = blockIdx.x * blockDim.x + threadIdx.x;
  const int n1 = 18 * 8 * 64 * 8;
  if (t < n1) {
    const int j = t & 7, lane = (t >> 3) & 63, nt = (t >> 9) & 7, kb = t >> 12;
    const int col = nt * 16 + (lane & 15);
    float val = 0.f;
    if (kb < 16) {
      const int k = kb * 32 + (lane >> 4) * 8 + j;
      val = W1[k * HID + col];
    } else {
      const int c = (kb - 16) * 32 + (lane >> 4) * 8 + j;
      const int k = (c == 0) ? 512 : ((c >= 2 && c < 34) ? (511 + c) : -1);
      if (k >= 0) val = W1[k * HID + col];
    }
    W1p[t] = f2bfbits(val);
  } else {
    const int t2 = t - n1;
    if (t2 < 4 * 8 * 64 * 8) {
      const int j = t2 & 7, lane = (t2 >> 3) & 63, nt = (t2 >> 9) & 7, kb = t2 >> 12;
      const int k = kb * 32 + (lane >> 4) * 8 + j;
      const int col = nt * 16 + (lane & 15);
      W2p[t2] = f2bfbits(W2[k * HID + col]);
    }
  }
}

// Edge-split: each wave owns 16 edges end-to-end (rows row0..row0+15 of the
// LDS tiles) -> no inter-wave LDS dependencies -> ZERO __syncthreads.
// Same-wave LDS write->read ordering is handled by the in-order DS pipe +
// compiler lgkmcnt. 3 waves/EU keeps reg cap ~170 (R3 lesson: incl. AGPRs).
__global__ __launch_bounds__(256, 3)
void edge_mlp(const float* __restrict__ z, const int* __restrict__ ei,
              const float* __restrict__ ea, const float* __restrict__ lre,
              const ushort* __restrict__ W1p, const float* __restrict__ b1,
              const ushort* __restrict__ W2p, const float* __restrict__ b2,
              const float* __restrict__ W3, const float* __restrict__ b3,
              float* __restrict__ out) {
  __shared__ ushort B0[ME * 128];  // 2 buffers * 16384B = 32768B
  __shared__ ushort B1[ME * 128];

  const int tid = threadIdx.x;
  const int lane = tid & 63;
  const int w = tid >> 6;
  const int r15 = lane & 15;
  const int g = lane >> 4;
  const int half = lane >> 5;    // 0/1
  const int li = lane & 31;
  const int row0 = w * 16;       // this wave's 16 edges
  const int eb = blockIdx.x * ME;

  // ---- per-wave metadata: lanes 0..15 = src idx, 16..31 = dst idx,
  //      lanes 32..47 = dist(f32), 48..63 = lr_id(f32)
  int sd = 0;
  float auxv = 0.f;
  if (lane < 16)      sd = ei[eb + row0 + lane];
  else if (lane < 32) sd = ei[N_EDGES + eb + row0 + (lane - 16)];
  else if (lane < 48) auxv = ea[(eb + row0 + (lane - 32)) * 7 + 0];
  else                auxv = ea[(eb + row0 + (lane - 48)) * 7 + 2];

  // ---- P0: gather zs,zd (same edge in same lane!), write bf16 zs->B0, zd->B1,
  //      compute prod/absdiff in f32 directly -> packed bf16 regs (abs folded
  //      into cvtpk input modifier). No unpack VALU later.
  uint2 pr_pk[8], ad_pk[8];
#pragma unroll
  for (int t = 0; t < 8; ++t) {
    const int e = 2 * t + half;
    const int r = row0 + e;
    const int s = __shfl(sd, e);
    const int d = __shfl(sd, 16 + e);
    const float4 a = *(const float4*)(z + s * HID + 4 * li);
    const float4 b = *(const float4*)(z + d * HID + 4 * li);
    uint2 zs, zd;
    zs.x = cvtpk(a.x, a.y); zs.y = cvtpk(a.z, a.w);
    zd.x = cvtpk(b.x, b.y); zd.y = cvtpk(b.z, b.w);
    *(uint2*)&B0[sidx(r, 4 * li)] = zs;
    *(uint2*)&B1[sidx(r, 4 * li)] = zd;
    pr_pk[t].x = cvtpk(a.x * b.x, a.y * b.y);
    pr_pk[t].y = cvtpk(a.z * b.z, a.w * b.w);
    ad_pk[t].x = cvtpk_abs(a.x - b.x, a.y - b.y);
    ad_pk[t].y = cvtpk_abs(a.z - b.z, a.w - b.w);
  }

  f32x4 acc1[8];
#pragma unroll
  for (int nt = 0; nt < 8; ++nt) acc1[nt] = (f32x4){0.f, 0.f, 0.f, 0.f};

  // One kb-step: A-frag from own rows of BUF, all 8 n-tiles of W.
#define MFMA_KB(BUF, WP, KBG, ACC)                                                      \
  {                                                                                     \
    const int kk_ = (KBG) & 3;                                                          \
    short8 af = *(const short8*)&BUF[sidx(row0 + r15, kk_ * 32 + g * 8)];               \
    _Pragma("unroll")                                                                   \
    for (int nt = 0; nt < 8; ++nt) {                                                    \
      short8 bfr = *(const short8*)(WP + ((((KBG) * 8 + nt) * 64) + lane) * 8);         \
      ACC[nt] = __builtin_amdgcn_mfma_f32_16x16x32_bf16(af, bfr, ACC[nt], 0, 0, 0);     \
    }                                                                                   \
  }

  // ---- layer 1, zs chunk (kb 0..3), then overwrite own B0 rows with prod
  __builtin_amdgcn_s_setprio(1);
#pragma unroll
  for (int kb = 0; kb < 4; ++kb) MFMA_KB(B0, W1p, kb, acc1)
  __builtin_amdgcn_s_setprio(0);
#pragma unroll
  for (int t = 0; t < 8; ++t)
    *(uint2*)&B0[sidx(row0 + 2 * t + half, 4 * li)] = pr_pk[t];

  // ---- zd chunk (kb 4..7), then overwrite own B1 rows with absdiff
  __builtin_amdgcn_s_setprio(1);
#pragma unroll
  for (int kb = 4; kb < 8; ++kb) MFMA_KB(B1, W1p, kb, acc1)
  __builtin_amdgcn_s_setprio(0);
#pragma unroll
  for (int t = 0; t < 8; ++t)
    *(uint2*)&B1[sidx(row0 + 2 * t + half, 4 * li)] = ad_pk[t];

  // ---- prod chunk (kb 8..11)
  __builtin_amdgcn_s_setprio(1);
#pragma unroll
  for (int kb = 8; kb < 12; ++kb) MFMA_KB(B0, W1p, kb, acc1)

  // ---- absdiff chunk (kb 12..15)
#pragma unroll
  for (int kb = 12; kb < 16; ++kb) MFMA_KB(B1, W1p, kb, acc1)
  __builtin_amdgcn_s_setprio(0);

  // ---- tail -> own B1 rows, cols 0..33 (col0 dist, 2..33 lr_emb; cols 34..63
  //      keep stale absdiff bf16 * zero weight rows = 0)
  {
    const float dv = __shfl(auxv, 32 + r15);
    if (lane < 16) B1[sidx(row0 + lane, 0)] = f2bfbits(dv);
  }
#pragma unroll
  for (int t = 0; t < 4; ++t) {
    const int e = 4 * t + g;
    const int lrid = (int)__shfl(auxv, 48 + e);
    const float2 lv = *(const float2*)(lre + lrid * 32 + 2 * r15);
    *(uint*)&B1[sidx(row0 + e, 2 + 2 * r15)] = cvtpk(lv.x, lv.y);
  }
  __builtin_amdgcn_s_setprio(1);
#pragma unroll
  for (int kb = 16; kb < 18; ++kb) MFMA_KB(B1, W1p, kb, acc1)
  __builtin_amdgcn_s_setprio(0);

  // ---- h1 = relu(acc1 + b1) -> own B0 rows (full 128 cols)
#pragma unroll
  for (int nt = 0; nt < 8; ++nt) {
    const float bv = b1[nt * 16 + r15];
#pragma unroll
    for (int j = 0; j < 4; ++j) {
      const float h = acc1[nt][j] + bv;
      B0[sidx(row0 + g * 4 + j, nt * 16 + r15)] = f2bfbits(fmaxf(h, 0.f));
    }
  }

  // ---- layer 2 (K=128) from own B0 rows
  f32x4 acc2[8];
#pragma unroll
  for (int nt = 0; nt < 8; ++nt) acc2[nt] = (f32x4){0.f, 0.f, 0.f, 0.f};
  __builtin_amdgcn_s_setprio(1);
#pragma unroll
  for (int kb = 0; kb < 4; ++kb) MFMA_KB(B0, W2p, kb, acc2)
  __builtin_amdgcn_s_setprio(0);

  // ---- h2 = relu(acc2 + b2) -> own B1 rows
#pragma unroll
  for (int nt = 0; nt < 8; ++nt) {
    const float bv = b2[nt * 16 + r15];
#pragma unroll
    for (int j = 0; j < 4; ++j) {
      const float h = acc2[nt][j] + bv;
      B1[sidx(row0 + g * 4 + j, nt * 16 + r15)] = f2bfbits(fmaxf(h, 0.f));
    }
  }

  // ---- layer 3: lane -> row row0+r15, cols g*32..g*32+31, reduce over g
  {
    float sum = 0.f;
#pragma unroll
    for (int i = 0; i < 4; ++i) {
      const int c0 = g * 32 + i * 8;
      const uint4 hv = *(const uint4*)&B1[sidx(row0 + r15, c0)];
#pragma unroll
      for (int p = 0; p < 4; ++p) {
        const uint u = ((const uint*)&hv)[p];
        const float2 wv = *(const float2*)(W3 + c0 + 2 * p);
        sum += blo(u) * wv.x + bhi(u) * wv.y;
      }
    }
    sum += __shfl_xor(sum, 16);
    sum += __shfl_xor(sum, 32);
    if (lane < 16) out[eb + row0 + r15] = sum + b3[0];
  }
}

extern "C" void kernel_launch(void* const* d_in, const int* in_sizes, int n_in,
                              void* d_out, int out_size, void* d_ws, size_t ws_size,
                              hipStream_t stream) {
  const float* z   = (const float*)d_in[0];
  const int*   ei  = (const int*)d_in[1];
  const float* ea  = (const float*)d_in[2];
  const float* lre = (const float*)d_in[3];
  const float* W1  = (const float*)d_in[4];
  const float* b1  = (const float*)d_in[5];
  const float* W2  = (const float*)d_in[6];
  const float* b2  = (const float*)d_in[7];
  const float* W3  = (const float*)d_in[8];
  const float* b3  = (const float*)d_in[9];
  float* out = (float*)d_out;

  ushort* W1p = (ushort*)d_ws;              // 18*8*64*8 = 73728 bf16
  ushort* W2p = W1p + 18 * 8 * 64 * 8;      // 4*8*64*8  = 16384 bf16

  prep_kernel<<<352, 256, 0, stream>>>(W1, W2, W1p, W2p);
  edge_mlp<<<N_EDGES / ME, 256, 0, stream>>>(z, ei, ea, lre, W1p, b1, W2p, b2, W3, b3, out);
}

// Round 6
// 328.758 us; speedup vs baseline: 1.7124x; 1.7124x over previous
//
#include <hip/hip_runtime.h>

#define N_EDGES 1000000
#define HID 128
#define ME 64          // edges per block (col-split: each wave owns 32 output cols)

typedef unsigned short ushort;
typedef unsigned int uint;
typedef __attribute__((ext_vector_type(8))) short short8;
typedef __attribute__((ext_vector_type(4))) float f32x4;

__device__ __forceinline__ float blo(uint u) { return __builtin_bit_cast(float, u << 16); }
__device__ __forceinline__ float bhi(uint u) { return __builtin_bit_cast(float, u & 0xffff0000u); }
__device__ __forceinline__ ushort f2bfbits(float f) {
  uint u = __builtin_bit_cast(uint, f);
  return (ushort)((u + 0x7fffu + ((u >> 16) & 1u)) >> 16);  // RNE
}
__device__ __forceinline__ uint cvtpk(float a, float b) {
  uint r;
  asm("v_cvt_pk_bf16_f32 %0, %1, %2" : "=v"(r) : "v"(a), "v"(b));
  return r;  // lo = bf16(a), hi = bf16(b)
}
__device__ __forceinline__ uint cvtpk_abs(float a, float b) {
  uint r;
  asm("v_cvt_pk_bf16_f32 %0, abs(%1), abs(%2)" : "=v"(r) : "v"(a), "v"(b));
  return r;
}
// XOR-swizzled element index into a [64][128] ushort LDS tile.
__device__ __forceinline__ int sidx(int r, int c) {
  return r * 128 + (c ^ ((r & 7) << 3));
}

// Pack W (row-major [K][128] f32) into B-fragment order for mfma_f32_16x16x32_bf16.
// W1p kb 0..15: k = kb*32 + (lane>>4)*8 + j (zs,zd,prod,absdiff).
// W1p kb 16..17 (tail chunk, 64 cols): c = (kb-16)*32+(lane>>4)*8+j;
//   c==0 -> k512 (dist); c in [2,34) -> k 511+c (lr_emb); else zero row.
__global__ void prep_kernel(const float* __restrict__ W1, const float* __restrict__ W2,
                            ushort* __restrict__ W1p, ushort* __restrict__ W2p) {
  const int t = blockIdx.x * blockDim.x + threadIdx.x;
  const int n1 = 18 * 8 * 64 * 8;
  if (t < n1) {
    const int j = t & 7, lane = (t >> 3) & 63, nt = (t >> 9) & 7, kb = t >> 12;
    const int col = nt * 16 + (lane & 15);
    float val = 0.f;
    if (kb < 16) {
      const int k = kb * 32 + (lane >> 4) * 8 + j;
      val = W1[k * HID + col];
    } else {
      const int c = (kb - 16) * 32 + (lane >> 4) * 8 + j;
      const int k = (c == 0) ? 512 : ((c >= 2 && c < 34) ? (511 + c) : -1);
      if (k >= 0) val = W1[k * HID + col];
    }
    W1p[t] = f2bfbits(val);
  } else {
    const int t2 = t - n1;
    if (t2 < 4 * 8 * 64 * 8) {
      const int j = t2 & 7, lane = (t2 >> 3) & 63, nt = (t2 >> 9) & 7, kb = t2 >> 12;
      const int k = kb * 32 + (lane >> 4) * 8 + j;
      const int col = nt * 16 + (lane & 15);
      W2p[t2] = f2bfbits(W2[k * HID + col]);
    }
  }
}

// Col-split (waves share W-panel reads: R5 lesson — W traffic is the constraint)
// + 3 LDS buffers so zs/zd/prod are all materialized at gather time -> one
// unbroken 12-kb MFMA run; 5 barriers total (R4 had 7).
// 3 waves/EU -> reg cap ~170 incl AGPRs: no spill (R2/R3 lesson).
__global__ __launch_bounds__(256, 3)
void edge_mlp(const float* __restrict__ z, const int* __restrict__ ei,
              const float* __restrict__ ea, const float* __restrict__ lre,
              const ushort* __restrict__ W1p, const float* __restrict__ b1,
              const ushort* __restrict__ W2p, const float* __restrict__ b2,
              const float* __restrict__ W3, const float* __restrict__ b3,
              float* __restrict__ out) {
  __shared__ ushort B0[ME * 128];  // 3 buffers * 16384B = 49152B -> 3 blocks/CU
  __shared__ ushort B1[ME * 128];
  __shared__ ushort B2[ME * 128];

  const int tid = threadIdx.x;
  const int lane = tid & 63;
  const int w = tid >> 6;        // wave 0..3, owns output cols [32w, 32w+32)
  const int r15 = lane & 15;
  const int g = lane >> 4;
  const int half = lane >> 5;    // 0/1
  const int li = lane & 31;
  const int row0 = w * 16;       // edges this wave gathers/builds
  const int cw = w * 32;
  const int eb = blockIdx.x * ME;

  // ---- per-wave metadata: lanes 0..15 = src idx, 16..31 = dst idx,
  //      lanes 32..47 = dist(f32), 48..63 = lr_id(f32)
  int sd = 0;
  float auxv = 0.f;
  if (lane < 16)      sd = ei[eb + row0 + lane];
  else if (lane < 32) sd = ei[N_EDGES + eb + row0 + (lane - 16)];
  else if (lane < 48) auxv = ea[(eb + row0 + (lane - 32)) * 7 + 0];
  else                auxv = ea[(eb + row0 + (lane - 48)) * 7 + 2];

  // ---- P0: gather zs,zd (same edge in same lane), write zs->B0, zd->B1,
  //      prod->B2 (computed f32 at gather); absdiff held in 16 regs.
  uint2 ad_pk[8];
#pragma unroll
  for (int t = 0; t < 8; ++t) {
    const int e = 2 * t + half;
    const int r = row0 + e;
    const int s = __shfl(sd, e);
    const int d = __shfl(sd, 16 + e);
    const float4 a = *(const float4*)(z + s * HID + 4 * li);
    const float4 b = *(const float4*)(z + d * HID + 4 * li);
    uint2 zs, zd, pr;
    zs.x = cvtpk(a.x, a.y); zs.y = cvtpk(a.z, a.w);
    zd.x = cvtpk(b.x, b.y); zd.y = cvtpk(b.z, b.w);
    pr.x = cvtpk(a.x * b.x, a.y * b.y);
    pr.y = cvtpk(a.z * b.z, a.w * b.w);
    *(uint2*)&B0[sidx(r, 4 * li)] = zs;
    *(uint2*)&B1[sidx(r, 4 * li)] = zd;
    *(uint2*)&B2[sidx(r, 4 * li)] = pr;
    ad_pk[t].x = cvtpk_abs(a.x - b.x, a.y - b.y);
    ad_pk[t].y = cvtpk_abs(a.z - b.z, a.w - b.w);
  }
  __syncthreads();

  f32x4 acc[4][2];
#pragma unroll
  for (int mt = 0; mt < 4; ++mt) {
    acc[mt][0] = (f32x4){0.f, 0.f, 0.f, 0.f};
    acc[mt][1] = (f32x4){0.f, 0.f, 0.f, 0.f};
  }

#define MFMA_CHUNK(BUF, NKK, KB)                                                        \
  _Pragma("unroll")                                                                     \
  for (int kk = 0; kk < (NKK); ++kk) {                                                  \
    const int kbg = (KB) + kk;                                                          \
    short8 bfr0 = *(const short8*)(W1p + (((kbg * 8 + 2 * w) * 64) + lane) * 8);        \
    short8 bfr1 = *(const short8*)(W1p + (((kbg * 8 + 2 * w + 1) * 64) + lane) * 8);    \
    _Pragma("unroll")                                                                   \
    for (int mt = 0; mt < 4; ++mt) {                                                    \
      short8 af = *(const short8*)&BUF[sidx(mt * 16 + r15, ((kbg) & 3) * 32 + g * 8)];  \
      acc[mt][0] = __builtin_amdgcn_mfma_f32_16x16x32_bf16(af, bfr0, acc[mt][0], 0, 0, 0); \
      acc[mt][1] = __builtin_amdgcn_mfma_f32_16x16x32_bf16(af, bfr1, acc[mt][1], 0, 0, 0); \
    }                                                                                   \
  }

  // ---- P1: one unbroken 12-kb MFMA run: zs (B0), zd (B1), prod (B2)
  __builtin_amdgcn_s_setprio(1);
  MFMA_CHUNK(B0, 4, 0)
  MFMA_CHUNK(B1, 4, 4)
  MFMA_CHUNK(B2, 4, 8)
  __builtin_amdgcn_s_setprio(0);
  __syncthreads();

  // ---- P2: absdiff -> B0 (from regs); tail -> B1 (col0 dist, cols 2..33 lr_emb;
  //      cols 34..63 stale zd * zero weight rows = 0)
#pragma unroll
  for (int t = 0; t < 8; ++t)
    *(uint2*)&B0[sidx(row0 + 2 * t + half, 4 * li)] = ad_pk[t];
  {
    const float dv = __shfl(auxv, 32 + r15);
    if (lane < 16) B1[sidx(row0 + lane, 0)] = f2bfbits(dv);
  }
#pragma unroll
  for (int t = 0; t < 4; ++t) {
    const int e = 4 * t + g;
    const int lrid = (int)__shfl(auxv, 48 + e);
    const float2 lv = *(const float2*)(lre + lrid * 32 + 2 * r15);
    *(uint*)&B1[sidx(row0 + e, 2 + 2 * r15)] = cvtpk(lv.x, lv.y);
  }
  __syncthreads();

  // ---- P3: MFMA absdiff (kb 12..15) + tail (kb 16..17); then h1 -> B2
  __builtin_amdgcn_s_setprio(1);
  MFMA_CHUNK(B0, 4, 12)
  MFMA_CHUNK(B1, 2, 16)
  __builtin_amdgcn_s_setprio(0);
  {
    const float b1v0 = b1[cw + r15];
    const float b1v1 = b1[cw + 16 + r15];
#pragma unroll
    for (int mt = 0; mt < 4; ++mt)
#pragma unroll
      for (int nt = 0; nt < 2; ++nt)
#pragma unroll
        for (int j = 0; j < 4; ++j) {
          const float h = acc[mt][nt][j] + (nt ? b1v1 : b1v0);
          B2[sidx(mt * 16 + g * 4 + j, cw + nt * 16 + r15)] = f2bfbits(fmaxf(h, 0.f));
        }
  }
  __syncthreads();

  // ---- P4: layer 2 (K=128) from B2; h2 -> B0
  f32x4 acc2[4][2];
#pragma unroll
  for (int mt = 0; mt < 4; ++mt) {
    acc2[mt][0] = (f32x4){0.f, 0.f, 0.f, 0.f};
    acc2[mt][1] = (f32x4){0.f, 0.f, 0.f, 0.f};
  }
  __builtin_amdgcn_s_setprio(1);
#pragma unroll
  for (int kk = 0; kk < 4; ++kk) {
    short8 bfr0 = *(const short8*)(W2p + (((kk * 8 + 2 * w) * 64) + lane) * 8);
    short8 bfr1 = *(const short8*)(W2p + (((kk * 8 + 2 * w + 1) * 64) + lane) * 8);
#pragma unroll
    for (int mt = 0; mt < 4; ++mt) {
      short8 af = *(const short8*)&B2[sidx(mt * 16 + r15, kk * 32 + g * 8)];
      acc2[mt][0] = __builtin_amdgcn_mfma_f32_16x16x32_bf16(af, bfr0, acc2[mt][0], 0, 0, 0);
      acc2[mt][1] = __builtin_amdgcn_mfma_f32_16x16x32_bf16(af, bfr1, acc2[mt][1], 0, 0, 0);
    }
  }
  __builtin_amdgcn_s_setprio(0);
  {
    const float b2v0 = b2[cw + r15];
    const float b2v1 = b2[cw + 16 + r15];
#pragma unroll
    for (int mt = 0; mt < 4; ++mt)
#pragma unroll
      for (int nt = 0; nt < 2; ++nt)
#pragma unroll
        for (int j = 0; j < 4; ++j) {
          const float h = acc2[mt][nt][j] + (nt ? b2v1 : b2v0);
          B0[sidx(mt * 16 + g * 4 + j, cw + nt * 16 + r15)] = f2bfbits(fmaxf(h, 0.f));
        }
  }
  __syncthreads();

  // ---- P5: layer 3 from B0: lane -> row w*16+r15, cols g*32..g*32+31
  {
    const int rr = w * 16 + r15;
    float sum = 0.f;
#pragma unroll
    for (int i = 0; i < 4; ++i) {
      const int c0 = g * 32 + i * 8;
      const uint4 hv = *(const uint4*)&B0[sidx(rr, c0)];
#pragma unroll
      for (int p = 0; p < 4; ++p) {
        const uint u = ((const uint*)&hv)[p];
        const float2 wv = *(const float2*)(W3 + c0 + 2 * p);
        sum += blo(u) * wv.x + bhi(u) * wv.y;
      }
    }
    sum += __shfl_xor(sum, 16);
    sum += __shfl_xor(sum, 32);
    if (lane < 16) out[eb + rr] = sum + b3[0];
  }
}

extern "C" void kernel_launch(void* const* d_in, const int* in_sizes, int n_in,
                              void* d_out, int out_size, void* d_ws, size_t ws_size,
                              hipStream_t stream) {
  const float* z   = (const float*)d_in[0];
  const int*   ei  = (const int*)d_in[1];
  const float* ea  = (const float*)d_in[2];
  const float* lre = (const float*)d_in[3];
  const float* W1  = (const float*)d_in[4];
  const float* b1  = (const float*)d_in[5];
  const float* W2  = (const float*)d_in[6];
  const float* b2  = (const float*)d_in[7];
  const float* W3  = (const float*)d_in[8];
  const float* b3  = (const float*)d_in[9];
  float* out = (float*)d_out;

  ushort* W1p = (ushort*)d_ws;              // 18*8*64*8 = 73728 bf16
  ushort* W2p = W1p + 18 * 8 * 64 * 8;      // 4*8*64*8  = 16384 bf16

  prep_kernel<<<352, 256, 0, stream>>>(W1, W2, W1p, W2p);
  edge_mlp<<<N_EDGES / ME, 256, 0, stream>>>(z, ei, ea, lre, W1p, b1, W2p, b2, W3, b3, out);
}

// Round 7
// 254.118 us; speedup vs baseline: 2.2154x; 1.2937x over previous
//
#include <hip/hip_runtime.h>

#define N_EDGES 1000000
#define HID 128
#define ME 64          // edges per block (col-split: each wave owns 32 output cols)

typedef unsigned short ushort;
typedef unsigned int uint;
typedef __attribute__((ext_vector_type(8))) short short8;
typedef __attribute__((ext_vector_type(4))) float f32x4;

__device__ __forceinline__ float blo(uint u) { return __builtin_bit_cast(float, u << 16); }
__device__ __forceinline__ float bhi(uint u) { return __builtin_bit_cast(float, u & 0xffff0000u); }
__device__ __forceinline__ ushort f2bfbits(float f) {
  uint u = __builtin_bit_cast(uint, f);
  return (ushort)((u + 0x7fffu + ((u >> 16) & 1u)) >> 16);  // RNE
}
__device__ __forceinline__ uint cvtpk(float a, float b) {
  uint r;
  asm("v_cvt_pk_bf16_f32 %0, %1, %2" : "=v"(r) : "v"(a), "v"(b));
  return r;  // lo = bf16(a), hi = bf16(b)
}
__device__ __forceinline__ uint cvtpk_abs(float a, float b) {
  uint r;
  asm("v_cvt_pk_bf16_f32 %0, abs(%1), abs(%2)" : "=v"(r) : "v"(a), "v"(b));
  return r;
}
// XOR-swizzled element index into a [64][128] ushort LDS tile.
__device__ __forceinline__ int sidx(int r, int c) {
  return r * 128 + (c ^ ((r & 7) << 3));
}

// Pack W (row-major [K][128] f32) into B-fragment order for mfma_f32_16x16x32_bf16.
// W1p kb 0..15: k = kb*32 + (lane>>4)*8 + j (zs,zd,prod,absdiff).
// W1p kb 16..17 (tail chunk, 64 cols): c = (kb-16)*32+(lane>>4)*8+j;
//   c==0 -> k512 (dist); c in [2,34) -> k 511+c (lr_emb); else zero row.
__global__ void prep_kernel(const float* __restrict__ W1, const float* __restrict__ W2,
                            ushort* __restrict__ W1p, ushort* __restrict__ W2p) {
  const int t = blockIdx.x * blockDim.x + threadIdx.x;
  const int n1 = 18 * 8 * 64 * 8;
  if (t < n1) {
    const int j = t & 7, lane = (t >> 3) & 63, nt = (t >> 9) & 7, kb = t >> 12;
    const int col = nt * 16 + (lane & 15);
    float val = 0.f;
    if (kb < 16) {
      const int k = kb * 32 + (lane >> 4) * 8 + j;
      val = W1[k * HID + col];
    } else {
      const int c = (kb - 16) * 32 + (lane >> 4) * 8 + j;
      const int k = (c == 0) ? 512 : ((c >= 2 && c < 34) ? (511 + c) : -1);
      if (k >= 0) val = W1[k * HID + col];
    }
    W1p[t] = f2bfbits(val);
  } else {
    const int t2 = t - n1;
    if (t2 < 4 * 8 * 64 * 8) {
      const int j = t2 & 7, lane = (t2 >> 3) & 63, nt = (t2 >> 9) & 7, kb = t2 >> 12;
      const int k = kb * 32 + (lane >> 4) * 8 + j;
      const int col = nt * 16 + (lane & 15);
      W2p[t2] = f2bfbits(W2[k * HID + col]);
    }
  }
}

// R7: 4 blocks/CU spill-free. Reg budget at (256,4) = 128/wave incl AGPRs:
//   single reused acc[4][2] = 32 AGPR; pr/ad held in 32 VGPR through P1;
//   ~84 arch VGPR total. 2 LDS buffers = 32KB. WRITE_SIZE is the spill tripwire.
__global__ __launch_bounds__(256, 4)
void edge_mlp(const float* __restrict__ z, const int* __restrict__ ei,
              const float* __restrict__ ea, const float* __restrict__ lre,
              const ushort* __restrict__ W1p, const float* __restrict__ b1,
              const ushort* __restrict__ W2p, const float* __restrict__ b2,
              const float* __restrict__ W3, const float* __restrict__ b3,
              float* __restrict__ out) {
  __shared__ ushort B0[ME * 128];  // 2 buffers * 16384B = 32768B
  __shared__ ushort B1[ME * 128];

  const int tid = threadIdx.x;
  const int lane = tid & 63;
  const int w = tid >> 6;        // wave 0..3, owns output cols [32w, 32w+32)
  const int r15 = lane & 15;
  const int g = lane >> 4;
  const int half = lane >> 5;    // 0/1
  const int li = lane & 31;
  const int row0 = w * 16;       // edges this wave gathers/builds
  const int cw = w * 32;
  const int eb = blockIdx.x * ME;

  // ---- per-wave metadata: lanes 0..15 = src idx, 16..31 = dst idx,
  //      lanes 32..47 = dist(f32), 48..63 = lr_id(f32)
  int sd = 0;
  float auxv = 0.f;
  if (lane < 16)      sd = ei[eb + row0 + lane];
  else if (lane < 32) sd = ei[N_EDGES + eb + row0 + (lane - 16)];
  else if (lane < 48) auxv = ea[(eb + row0 + (lane - 32)) * 7 + 0];
  else                auxv = ea[(eb + row0 + (lane - 48)) * 7 + 2];

  // ---- P0: gather zs,zd (same edge in same lane), write zs->B0, zd->B1;
  //      prod/absdiff computed in f32 NOW, held packed in 32 VGPRs.
  uint2 pr_pk[8], ad_pk[8];
#pragma unroll
  for (int t = 0; t < 8; ++t) {
    const int e = 2 * t + half;
    const int r = row0 + e;
    const int s = __shfl(sd, e);
    const int d = __shfl(sd, 16 + e);
    const float4 a = *(const float4*)(z + s * HID + 4 * li);
    const float4 b = *(const float4*)(z + d * HID + 4 * li);
    uint2 zs, zd;
    zs.x = cvtpk(a.x, a.y); zs.y = cvtpk(a.z, a.w);
    zd.x = cvtpk(b.x, b.y); zd.y = cvtpk(b.z, b.w);
    *(uint2*)&B0[sidx(r, 4 * li)] = zs;
    *(uint2*)&B1[sidx(r, 4 * li)] = zd;
    pr_pk[t].x = cvtpk(a.x * b.x, a.y * b.y);
    pr_pk[t].y = cvtpk(a.z * b.z, a.w * b.w);
    ad_pk[t].x = cvtpk_abs(a.x - b.x, a.y - b.y);
    ad_pk[t].y = cvtpk_abs(a.z - b.z, a.w - b.w);
  }
  __syncthreads();

  f32x4 acc[4][2];   // reused for layer 1 AND layer 2 -> 32 AGPRs total
#pragma unroll
  for (int mt = 0; mt < 4; ++mt) {
    acc[mt][0] = (f32x4){0.f, 0.f, 0.f, 0.f};
    acc[mt][1] = (f32x4){0.f, 0.f, 0.f, 0.f};
  }

#define MFMA_CHUNK(BUF, NKK, KB)                                                        \
  _Pragma("unroll")                                                                     \
  for (int kk = 0; kk < (NKK); ++kk) {                                                  \
    const int kbg = (KB) + kk;                                                          \
    short8 bfr0 = *(const short8*)(W1p + (((kbg * 8 + 2 * w) * 64) + lane) * 8);        \
    short8 bfr1 = *(const short8*)(W1p + (((kbg * 8 + 2 * w + 1) * 64) + lane) * 8);    \
    _Pragma("unroll")                                                                   \
    for (int mt = 0; mt < 4; ++mt) {                                                    \
      short8 af = *(const short8*)&BUF[sidx(mt * 16 + r15, ((kbg) & 3) * 32 + g * 8)];  \
      acc[mt][0] = __builtin_amdgcn_mfma_f32_16x16x32_bf16(af, bfr0, acc[mt][0], 0, 0, 0); \
      acc[mt][1] = __builtin_amdgcn_mfma_f32_16x16x32_bf16(af, bfr1, acc[mt][1], 0, 0, 0); \
    }                                                                                   \
  }

  // ---- P1: MFMA zs (kb 0..3)
  __builtin_amdgcn_s_setprio(1);
  MFMA_CHUNK(B0, 4, 0)
  __builtin_amdgcn_s_setprio(0);
  __syncthreads();

  // ---- P2: prod -> B0 (pure stores from regs); MFMA zd (kb 4..7)
#pragma unroll
  for (int t = 0; t < 8; ++t)
    *(uint2*)&B0[sidx(row0 + 2 * t + half, 4 * li)] = pr_pk[t];
  __builtin_amdgcn_s_setprio(1);
  MFMA_CHUNK(B1, 4, 4)
  __builtin_amdgcn_s_setprio(0);
  __syncthreads();

  // ---- P3: absdiff -> B1 (pure stores); MFMA prod (kb 8..11)
#pragma unroll
  for (int t = 0; t < 8; ++t)
    *(uint2*)&B1[sidx(row0 + 2 * t + half, 4 * li)] = ad_pk[t];
  __builtin_amdgcn_s_setprio(1);
  MFMA_CHUNK(B0, 4, 8)
  __builtin_amdgcn_s_setprio(0);
  __syncthreads();

  // ---- P4: tail -> B0 (col0 dist, cols 2..33 lr_emb; cols 34..63 stale prod
  //      * zero weight rows = 0); MFMA absdiff (kb 12..15)
  {
    const float dv = __shfl(auxv, 32 + r15);
    if (lane < 16) B0[sidx(row0 + lane, 0)] = f2bfbits(dv);
  }
#pragma unroll
  for (int t = 0; t < 4; ++t) {
    const int e = 4 * t + g;
    const int lrid = (int)__shfl(auxv, 48 + e);
    const float2 lv = *(const float2*)(lre + lrid * 32 + 2 * r15);
    *(uint*)&B0[sidx(row0 + e, 2 + 2 * r15)] = cvtpk(lv.x, lv.y);
  }
  __builtin_amdgcn_s_setprio(1);
  MFMA_CHUNK(B1, 4, 12)
  __builtin_amdgcn_s_setprio(0);
  __syncthreads();

  // ---- P5: MFMA tail (kb 16..17); h1 = relu(acc+b1) -> B1
  __builtin_amdgcn_s_setprio(1);
  MFMA_CHUNK(B0, 2, 16)
  __builtin_amdgcn_s_setprio(0);
  {
    const float b1v0 = b1[cw + r15];
    const float b1v1 = b1[cw + 16 + r15];
#pragma unroll
    for (int mt = 0; mt < 4; ++mt)
#pragma unroll
      for (int nt = 0; nt < 2; ++nt)
#pragma unroll
        for (int j = 0; j < 4; ++j) {
          const float h = acc[mt][nt][j] + (nt ? b1v1 : b1v0);
          B1[sidx(mt * 16 + g * 4 + j, cw + nt * 16 + r15)] = f2bfbits(fmaxf(h, 0.f));
        }
  }
  __syncthreads();

  // ---- P6: layer 2 (K=128) from B1 (acc re-zeroed/reused); h2 -> B0
#pragma unroll
  for (int mt = 0; mt < 4; ++mt) {
    acc[mt][0] = (f32x4){0.f, 0.f, 0.f, 0.f};
    acc[mt][1] = (f32x4){0.f, 0.f, 0.f, 0.f};
  }
  __builtin_amdgcn_s_setprio(1);
#pragma unroll
  for (int kk = 0; kk < 4; ++kk) {
    short8 bfr0 = *(const short8*)(W2p + (((kk * 8 + 2 * w) * 64) + lane) * 8);
    short8 bfr1 = *(const short8*)(W2p + (((kk * 8 + 2 * w + 1) * 64) + lane) * 8);
#pragma unroll
    for (int mt = 0; mt < 4; ++mt) {
      short8 af = *(const short8*)&B1[sidx(mt * 16 + r15, kk * 32 + g * 8)];
      acc[mt][0] = __builtin_amdgcn_mfma_f32_16x16x32_bf16(af, bfr0, acc[mt][0], 0, 0, 0);
      acc[mt][1] = __builtin_amdgcn_mfma_f32_16x16x32_bf16(af, bfr1, acc[mt][1], 0, 0, 0);
    }
  }
  __builtin_amdgcn_s_setprio(0);
  {
    const float b2v0 = b2[cw + r15];
    const float b2v1 = b2[cw + 16 + r15];
#pragma unroll
    for (int mt = 0; mt < 4; ++mt)
#pragma unroll
      for (int nt = 0; nt < 2; ++nt)
#pragma unroll
        for (int j = 0; j < 4; ++j) {
          const float h = acc[mt][nt][j] + (nt ? b2v1 : b2v0);
          B0[sidx(mt * 16 + g * 4 + j, cw + nt * 16 + r15)] = f2bfbits(fmaxf(h, 0.f));
        }
  }
  __syncthreads();

  // ---- P7: layer 3 from B0: lane -> row w*16+r15, cols g*32..g*32+31
  {
    const int rr = w * 16 + r15;
    float sum = 0.f;
#pragma unroll
    for (int i = 0; i < 4; ++i) {
      const int c0 = g * 32 + i * 8;
      const uint4 hv = *(const uint4*)&B0[sidx(rr, c0)];
#pragma unroll
      for (int p = 0; p < 4; ++p) {
        const uint u = ((const uint*)&hv)[p];
        const float2 wv = *(const float2*)(W3 + c0 + 2 * p);
        sum += blo(u) * wv.x + bhi(u) * wv.y;
      }
    }
    sum += __shfl_xor(sum, 16);
    sum += __shfl_xor(sum, 32);
    if (lane < 16) out[eb + rr] = sum + b3[0];
  }
}

extern "C" void kernel_launch(void* const* d_in, const int* in_sizes, int n_in,
                              void* d_out, int out_size, void* d_ws, size_t ws_size,
                              hipStream_t stream) {
  const float* z   = (const float*)d_in[0];
  const int*   ei  = (const int*)d_in[1];
  const float* ea  = (const float*)d_in[2];
  const float* lre = (const float*)d_in[3];
  const float* W1  = (const float*)d_in[4];
  const float* b1  = (const float*)d_in[5];
  const float* W2  = (const float*)d_in[6];
  const float* b2  = (const float*)d_in[7];
  const float* W3  = (const float*)d_in[8];
  const float* b3  = (const float*)d_in[9];
  float* out = (float*)d_out;

  ushort* W1p = (ushort*)d_ws;              // 18*8*64*8 = 73728 bf16
  ushort* W2p = W1p + 18 * 8 * 64 * 8;      // 4*8*64*8  = 16384 bf16

  prep_kernel<<<352, 256, 0, stream>>>(W1, W2, W1p, W2p);
  edge_mlp<<<N_EDGES / ME, 256, 0, stream>>>(z, ei, ea, lre, W1p, b1, W2p, b2, W3, b3, out);
}